// Round 6
// baseline (227.955 us; speedup 1.0000x reference)
//
#include <hip/hip_runtime.h>
#include <float.h>
#include <stdint.h>

// CorrLoss via bf16 MFMA, symmetric tiles, occupancy-first:
//   k0: cast feat fp32 -> bf16 (RNE); init monotone-key min/max arrays + counter
//   k1: 2080 upper-tri 64x64 tiles (8 blocks/CU), 256 thr = 4 waves, each wave
//       a 32x32 quadrant (2x2 mfma_f32_16x16x32_bf16 frags). LDS-staged via
//       global_load_lds w=16 (1 instr per thread per tile per k-step). Masked
//       per-row min/max (direct + transposed) folded via device-scope
//       atomicMin/Max on order-preserving uint keys. Last finishing block
//       folds the 32 KB of keys -> out[0]. 2 dispatches total.

#define N_ROWS 4096
#define D_K    512
#define BT     64
#define BK     32
#define NTB    (N_ROWS / BT)           // 64
#define NTILES (NTB * (NTB + 1) / 2)   // 2080
#define MARGIN 40.0f

typedef __bf16 bf16_t;
typedef bf16_t bf16x8 __attribute__((ext_vector_type(8)));
typedef float  floatx4 __attribute__((ext_vector_type(4)));
typedef unsigned short ushort_t;
typedef ushort_t ushortx8 __attribute__((ext_vector_type(8)));

#define GLOAD_LDS16(g, l)                                        \
    __builtin_amdgcn_global_load_lds(                            \
        (const __attribute__((address_space(1))) void*)(g),      \
        (__attribute__((address_space(3))) void*)(l), 16, 0, 0)

__device__ __forceinline__ ushort_t f2bf_rne(float x) {
    uint32_t u = __builtin_bit_cast(uint32_t, x);
    return (ushort_t)((u + 0x7FFFu + ((u >> 16) & 1u)) >> 16);
}

// order-preserving float <-> uint key (larger float => larger key)
__device__ __forceinline__ unsigned fkey(float f) {
    unsigned u = __builtin_bit_cast(unsigned, f);
    return (u & 0x80000000u) ? ~u : (u | 0x80000000u);
}
__device__ __forceinline__ float funkey(unsigned k) {
    unsigned u = (k & 0x80000000u) ? (k & 0x7FFFFFFFu) : ~k;
    return __builtin_bit_cast(float, u);
}

__global__ __launch_bounds__(256) void cast_kernel(
    const float* __restrict__ f, ushort_t* __restrict__ o,
    unsigned* __restrict__ ap_key, unsigned* __restrict__ an_key,
    int* __restrict__ counter)
{
    const int gid = blockIdx.x * 256 + threadIdx.x;
    if (gid < N_ROWS) { ap_key[gid] = 0xFFFFFFFFu; an_key[gid] = 0u; }
    if (gid == 0) *counter = 0;

    const int i = gid * 8;
    const float4 v0 = *(const float4*)(f + i);
    const float4 v1 = *(const float4*)(f + i + 4);
    ushortx8 r;
    r[0] = f2bf_rne(v0.x); r[1] = f2bf_rne(v0.y);
    r[2] = f2bf_rne(v0.z); r[3] = f2bf_rne(v0.w);
    r[4] = f2bf_rne(v1.x); r[5] = f2bf_rne(v1.y);
    r[6] = f2bf_rne(v1.z); r[7] = f2bf_rne(v1.w);
    *(ushortx8*)(o + i) = r;
}

__global__ __launch_bounds__(256) void gram_mfma_kernel(
    const ushort_t* __restrict__ fb, const int* __restrict__ tgt,
    unsigned* __restrict__ ap_key, unsigned* __restrict__ an_key,
    int* __restrict__ counter, float* __restrict__ out)
{
    __shared__ __align__(16) ushort_t As[BT * BK];   // 4 KB, [row][k]
    __shared__ __align__(16) ushort_t Bs[BT * BK];   // 4 KB
    __shared__ int tgI[BT];
    __shared__ int tgJ[BT];
    __shared__ float sred[4];
    __shared__ int lastFlag;

    // flat block id -> upper-tri (bi, bj), row-major
    int bi = 0, rem = blockIdx.x;
    while (rem >= NTB - bi) { rem -= NTB - bi; ++bi; }
    const int bj = bi + rem;

    const int tid  = threadIdx.x;
    const int i0   = bi * BT;
    const int j0   = bj * BT;
    const int lane = tid & 63;
    const int wave = tid >> 6;
    const int wr   = wave >> 1;      // row half (0/1)
    const int wc   = wave & 1;       // col half (0/1)
    const int lr   = lane & 15;      // frag row (A/B) / col (C/D)
    const int lg   = lane >> 4;      // k-group (A/B) / row-quad (C/D)

    if (tid < BT)            tgI[tid]      = tgt[i0 + tid];
    else if (tid < 2 * BT)   tgJ[tid - BT] = tgt[j0 + tid - BT];

    // staging: thread t loads 16 B = 8 bf16 of tile-row (t>>2), k-quad (t&3)
    const int srow = tid >> 2;
    const int skq  = tid & 3;
    const size_t gA0 = (size_t)(i0 + srow) * D_K + skq * 8;
    const size_t gB0 = (size_t)(j0 + srow) * D_K + skq * 8;
    char* AsB = (char*)As;
    char* BsB = (char*)Bs;

    floatx4 acc[2][2];
#pragma unroll
    for (int a = 0; a < 2; ++a)
#pragma unroll
        for (int b = 0; b < 2; ++b) acc[a][b] = (floatx4)0.0f;

    for (int k0 = 0; k0 < D_K; k0 += BK) {
        GLOAD_LDS16(fb + gA0 + k0, AsB + tid * 16);
        GLOAD_LDS16(fb + gB0 + k0, BsB + tid * 16);
        __syncthreads();

        bf16x8 af[2], bf[2];
#pragma unroll
        for (int rg = 0; rg < 2; ++rg)
            af[rg] = *(const bf16x8*)(As + ((wr * 32 + rg * 16 + lr) * BK + lg * 8));
#pragma unroll
        for (int cg = 0; cg < 2; ++cg)
            bf[cg] = *(const bf16x8*)(Bs + ((wc * 32 + cg * 16 + lr) * BK + lg * 8));
#pragma unroll
        for (int rg = 0; rg < 2; ++rg)
#pragma unroll
            for (int cg = 0; cg < 2; ++cg)
                acc[rg][cg] = __builtin_amdgcn_mfma_f32_16x16x32_bf16(
                    af[rg], bf[cg], acc[rg][cg], 0, 0, 0);
        __syncthreads();
    }

    // ---- epilogue: C/D frag layout: col = lr, row = lg*4 + reg ----
    int tj[2];
#pragma unroll
    for (int cg = 0; cg < 2; ++cg) tj[cg] = tgJ[wc * 32 + cg * 16 + lr];

    float apT[2], anT[2];
#pragma unroll
    for (int cg = 0; cg < 2; ++cg) { apT[cg] = FLT_MAX; anT[cg] = -FLT_MAX; }

#pragma unroll
    for (int rg = 0; rg < 2; ++rg) {
#pragma unroll
        for (int r = 0; r < 4; ++r) {
            const int rloc = wr * 32 + rg * 16 + lg * 4 + r;
            const int ti = tgI[rloc];
            float vap = FLT_MAX, van = -FLT_MAX;
#pragma unroll
            for (int cg = 0; cg < 2; ++cg) {
                const float v = acc[rg][cg][r];
                if (ti == tj[cg]) { vap = fminf(vap, v); apT[cg] = fminf(apT[cg], v); }
                else              { van = fmaxf(van, v); anT[cg] = fmaxf(anT[cg], v); }
            }
            // direct: reduce over 16 cols (lanes differing in lr bits)
#pragma unroll
            for (int m = 1; m < 16; m <<= 1) {
                vap = fminf(vap, __shfl_xor(vap, m));
                van = fmaxf(van, __shfl_xor(van, m));
            }
            if (lr == 0) {   // lanes 0,16,32,48 -> 4 distinct rows
                atomicMin(&ap_key[i0 + rloc], fkey(vap));
                atomicMax(&an_key[i0 + rloc], fkey(van));
            }
        }
    }
    if (bi != bj) {
        // transposed: reduce over the 4 lane-groups (rows folded in-lane)
#pragma unroll
        for (int cg = 0; cg < 2; ++cg) {
            float vap = apT[cg], van = anT[cg];
            vap = fminf(vap, __shfl_xor(vap, 16)); van = fmaxf(van, __shfl_xor(van, 16));
            vap = fminf(vap, __shfl_xor(vap, 32)); van = fmaxf(van, __shfl_xor(van, 32));
            if (lg == 0) {   // lanes 0..15 -> 16 distinct cols
                atomicMin(&ap_key[j0 + wc * 32 + cg * 16 + lr], fkey(vap));
                atomicMax(&an_key[j0 + wc * 32 + cg * 16 + lr], fkey(van));
            }
        }
    }

    // ---- last-block fold ----
    __threadfence();
    __syncthreads();
    if (tid == 0) lastFlag = (atomicAdd(counter, 1) == NTILES - 1);
    __syncthreads();
    if (!lastFlag) return;
    __threadfence();

    float local = 0.0f;
    for (int r = tid; r < N_ROWS; r += 256) {
        const float ap = funkey(ap_key[r]);
        const float an = funkey(an_key[r]);
        const float v = an - ap + MARGIN;
        local += (v > 0.0f) ? v : 0.0f;
    }
#pragma unroll
    for (int m = 32; m >= 1; m >>= 1) local += __shfl_down(local, m);
    if (lane == 0) sred[wave] = local;
    __syncthreads();
    if (tid == 0)
        out[0] = (sred[0] + sred[1] + sred[2] + sred[3]) * (1.0f / N_ROWS);
}

extern "C" void kernel_launch(void* const* d_in, const int* in_sizes, int n_in,
                              void* d_out, int out_size, void* d_ws, size_t ws_size,
                              hipStream_t stream)
{
    const float* feat = (const float*)d_in[0];
    const int*   tgt  = (const int*)d_in[1];

    ushort_t* fb      = (ushort_t*)d_ws;                        // 4 MB bf16 feat
    unsigned* ap_key  = (unsigned*)(fb + (size_t)N_ROWS * D_K); // 16 KB
    unsigned* an_key  = ap_key + N_ROWS;                        // 16 KB
    int*      counter = (int*)(an_key + N_ROWS);

    cast_kernel<<<(N_ROWS * D_K) / (256 * 8), 256, 0, stream>>>(
        feat, fb, ap_key, an_key, counter);
    gram_mfma_kernel<<<NTILES, 256, 0, stream>>>(
        fb, tgt, ap_key, an_key, counter, (float*)d_out);
}

// Round 7
// 94.760 us; speedup vs baseline: 2.4056x; 2.4056x over previous
//
#include <hip/hip_runtime.h>
#include <float.h>
#include <stdint.h>

// CorrLoss via bf16 MFMA, symmetric 64x64 tiles, NO value-path atomics:
//   k0: cast feat fp32 -> bf16 (RNE); zero the fold done-counter.
//   k1: 2080 upper-tri 64x64 tiles (8 blocks/CU), 4 waves/block, each wave a
//       32x32 quadrant. LDS-staged (global_load_lds w=16). Epilogue: LDS
//       cross-wave reduce, then EXACTLY-ONCE partial writes: cell (r,s) of
//       part[s][row] from tile (r,s) direct when s>=r, tile (s,r) transposed
//       when s<r. No atomics, no init needed.
//   k2: 16-block fold, 1 row/thread over 64 slices (coalesced, L2-resident),
//       block sums -> ws, done-counter last block writes out[0].

#define N_ROWS 4096
#define D_K    512
#define BT     64
#define BK     32
#define NTB    (N_ROWS / BT)           // 64
#define NTILES (NTB * (NTB + 1) / 2)   // 2080
#define MARGIN 40.0f
#define FOLD_BLOCKS 16

typedef __bf16 bf16_t;
typedef bf16_t bf16x8 __attribute__((ext_vector_type(8)));
typedef float  floatx4 __attribute__((ext_vector_type(4)));
typedef unsigned short ushort_t;
typedef ushort_t ushortx8 __attribute__((ext_vector_type(8)));

#define GLOAD_LDS16(g, l)                                        \
    __builtin_amdgcn_global_load_lds(                            \
        (const __attribute__((address_space(1))) void*)(g),      \
        (__attribute__((address_space(3))) void*)(l), 16, 0, 0)

__device__ __forceinline__ ushort_t f2bf_rne(float x) {
    uint32_t u = __builtin_bit_cast(uint32_t, x);
    return (ushort_t)((u + 0x7FFFu + ((u >> 16) & 1u)) >> 16);
}

__global__ __launch_bounds__(256) void cast_kernel(
    const float* __restrict__ f, ushort_t* __restrict__ o,
    int* __restrict__ counter)
{
    const int gid = blockIdx.x * 256 + threadIdx.x;
    if (gid == 0) *counter = 0;

    const int i = gid * 8;
    const float4 v0 = *(const float4*)(f + i);
    const float4 v1 = *(const float4*)(f + i + 4);
    ushortx8 r;
    r[0] = f2bf_rne(v0.x); r[1] = f2bf_rne(v0.y);
    r[2] = f2bf_rne(v0.z); r[3] = f2bf_rne(v0.w);
    r[4] = f2bf_rne(v1.x); r[5] = f2bf_rne(v1.y);
    r[6] = f2bf_rne(v1.z); r[7] = f2bf_rne(v1.w);
    *(ushortx8*)(o + i) = r;
}

__global__ __launch_bounds__(256) void gram_mfma_kernel(
    const ushort_t* __restrict__ fb, const int* __restrict__ tgt,
    float* __restrict__ ap_part, float* __restrict__ an_part)
{
    __shared__ __align__(16) ushort_t As[BT * BK];   // 4 KB, [row][k]
    __shared__ __align__(16) ushort_t Bs[BT * BK];   // 4 KB
    __shared__ int tgI[BT];
    __shared__ int tgJ[BT];
    __shared__ float apRed[2][BT],  anRed[2][BT];    // direct, by wc
    __shared__ float apRedT[2][BT], anRedT[2][BT];   // transposed, by wr

    // flat block id -> upper-tri (bi, bj), row-major
    int bi = 0, rem = blockIdx.x;
    while (rem >= NTB - bi) { rem -= NTB - bi; ++bi; }
    const int bj = bi + rem;

    const int tid  = threadIdx.x;
    const int i0   = bi * BT;
    const int j0   = bj * BT;
    const int lane = tid & 63;
    const int wave = tid >> 6;
    const int wr   = wave >> 1;      // row half (0/1)
    const int wc   = wave & 1;       // col half (0/1)
    const int lr   = lane & 15;      // frag row (A/B) / col (C/D)
    const int lg   = lane >> 4;      // k-group (A/B) / row-quad (C/D)

    if (tid < BT)            tgI[tid]      = tgt[i0 + tid];
    else if (tid < 2 * BT)   tgJ[tid - BT] = tgt[j0 + tid - BT];

    // staging: thread t loads 16 B = 8 bf16 of tile-row (t>>2), k-quad (t&3)
    const int srow = tid >> 2;
    const int skq  = tid & 3;
    const size_t gA0 = (size_t)(i0 + srow) * D_K + skq * 8;
    const size_t gB0 = (size_t)(j0 + srow) * D_K + skq * 8;
    char* AsB = (char*)As;
    char* BsB = (char*)Bs;

    floatx4 acc[2][2];
#pragma unroll
    for (int a = 0; a < 2; ++a)
#pragma unroll
        for (int b = 0; b < 2; ++b) acc[a][b] = (floatx4)0.0f;

    for (int k0 = 0; k0 < D_K; k0 += BK) {
        GLOAD_LDS16(fb + gA0 + k0, AsB + tid * 16);
        GLOAD_LDS16(fb + gB0 + k0, BsB + tid * 16);
        __syncthreads();

        bf16x8 af[2], bf[2];
#pragma unroll
        for (int rg = 0; rg < 2; ++rg)
            af[rg] = *(const bf16x8*)(As + ((wr * 32 + rg * 16 + lr) * BK + lg * 8));
#pragma unroll
        for (int cg = 0; cg < 2; ++cg)
            bf[cg] = *(const bf16x8*)(Bs + ((wc * 32 + cg * 16 + lr) * BK + lg * 8));
#pragma unroll
        for (int rg = 0; rg < 2; ++rg)
#pragma unroll
            for (int cg = 0; cg < 2; ++cg)
                acc[rg][cg] = __builtin_amdgcn_mfma_f32_16x16x32_bf16(
                    af[rg], bf[cg], acc[rg][cg], 0, 0, 0);
        __syncthreads();
    }

    // ---- epilogue: C/D frag layout: col = lr, row = lg*4 + reg ----
    int tj[2];
#pragma unroll
    for (int cg = 0; cg < 2; ++cg) tj[cg] = tgJ[wc * 32 + cg * 16 + lr];

    float apT[2], anT[2];
#pragma unroll
    for (int cg = 0; cg < 2; ++cg) { apT[cg] = FLT_MAX; anT[cg] = -FLT_MAX; }

#pragma unroll
    for (int rg = 0; rg < 2; ++rg) {
#pragma unroll
        for (int r = 0; r < 4; ++r) {
            const int rloc = wr * 32 + rg * 16 + lg * 4 + r;
            const int ti = tgI[rloc];
            float vap = FLT_MAX, van = -FLT_MAX;
#pragma unroll
            for (int cg = 0; cg < 2; ++cg) {
                const float v = acc[rg][cg][r];
                if (ti == tj[cg]) { vap = fminf(vap, v); apT[cg] = fminf(apT[cg], v); }
                else              { van = fmaxf(van, v); anT[cg] = fmaxf(anT[cg], v); }
            }
            // direct: fold the 16 cols held by lanes lr=0..15
#pragma unroll
            for (int m = 1; m < 16; m <<= 1) {
                vap = fminf(vap, __shfl_xor(vap, m));
                van = fmaxf(van, __shfl_xor(van, m));
            }
            if (lr == 0) { apRed[wc][rloc] = vap; anRed[wc][rloc] = van; }
        }
    }
    // transposed: rows already folded in-lane; fold the 4 lane-groups
#pragma unroll
    for (int cg = 0; cg < 2; ++cg) {
        float vap = apT[cg], van = anT[cg];
        vap = fminf(vap, __shfl_xor(vap, 16)); van = fmaxf(van, __shfl_xor(van, 16));
        vap = fminf(vap, __shfl_xor(vap, 32)); van = fmaxf(van, __shfl_xor(van, 32));
        if (lg == 0) {
            apRedT[wr][wc * 32 + cg * 16 + lr] = vap;
            anRedT[wr][wc * 32 + cg * 16 + lr] = van;
        }
    }
    __syncthreads();

    if (tid < BT) {
        ap_part[(size_t)bj * N_ROWS + i0 + tid] = fminf(apRed[0][tid], apRed[1][tid]);
        an_part[(size_t)bj * N_ROWS + i0 + tid] = fmaxf(anRed[0][tid], anRed[1][tid]);
        if (bi != bj) {
            ap_part[(size_t)bi * N_ROWS + j0 + tid] = fminf(apRedT[0][tid], apRedT[1][tid]);
            an_part[(size_t)bi * N_ROWS + j0 + tid] = fmaxf(anRedT[0][tid], anRedT[1][tid]);
        }
    }
}

__global__ __launch_bounds__(256) void fold_kernel(
    const float* __restrict__ ap_part, const float* __restrict__ an_part,
    float* __restrict__ blk_sum, int* __restrict__ counter,
    float* __restrict__ out)
{
    __shared__ float sred[4];
    const int tid = threadIdx.x;
    const int row = blockIdx.x * 256 + tid;
    const int lane = tid & 63;
    const int wave = tid >> 6;

    float ap = FLT_MAX, an = -FLT_MAX;
#pragma unroll 8
    for (int s = 0; s < NTB; ++s) {
        ap = fminf(ap, ap_part[(size_t)s * N_ROWS + row]);
        an = fmaxf(an, an_part[(size_t)s * N_ROWS + row]);
    }
    const float v = an - ap + MARGIN;
    float local = (v > 0.0f) ? v : 0.0f;
#pragma unroll
    for (int m = 32; m >= 1; m >>= 1) local += __shfl_down(local, m);
    if (lane == 0) sred[wave] = local;
    __syncthreads();

    if (tid == 0) {
        blk_sum[blockIdx.x] = sred[0] + sred[1] + sred[2] + sred[3];
        __threadfence();
        if (atomicAdd(counter, 1) == FOLD_BLOCKS - 1) {
            __threadfence();
            float s = 0.0f;
#pragma unroll
            for (int b = 0; b < FOLD_BLOCKS; ++b) s += blk_sum[b];
            out[0] = s * (1.0f / N_ROWS);
        }
    }
}

extern "C" void kernel_launch(void* const* d_in, const int* in_sizes, int n_in,
                              void* d_out, int out_size, void* d_ws, size_t ws_size,
                              hipStream_t stream)
{
    const float* feat = (const float*)d_in[0];
    const int*   tgt  = (const int*)d_in[1];

    ushort_t* fb      = (ushort_t*)d_ws;                        // 4 MB bf16 feat
    float*    ap_part = (float*)(fb + (size_t)N_ROWS * D_K);    // 1 MB
    float*    an_part = ap_part + (size_t)NTB * N_ROWS;         // 1 MB
    float*    blk_sum = an_part + (size_t)NTB * N_ROWS;         // 64 B
    int*      counter = (int*)(blk_sum + FOLD_BLOCKS);

    cast_kernel<<<(N_ROWS * D_K) / (256 * 8), 256, 0, stream>>>(feat, fb, counter);
    gram_mfma_kernel<<<NTILES, 256, 0, stream>>>(fb, tgt, ap_part, an_part);
    fold_kernel<<<FOLD_BLOCKS, 256, 0, stream>>>(ap_part, an_part, blk_sum,
                                                 counter, (float*)d_out);
}

// Round 8
// 86.753 us; speedup vs baseline: 2.6276x; 1.0923x over previous
//
#include <hip/hip_runtime.h>
#include <float.h>
#include <stdint.h>

// CorrLoss via bf16 MFMA, symmetric 128x128 tiles, swizzled LDS, no atomics:
//   k0: cast feat fp32 -> bf16 (RNE); zero fold done-counter.
//   k1: 528 upper-tri 128x128 tiles, 512 thr = 8 waves, each wave a 64x32
//       patch (4x2 mfma_f32_16x16x32_bf16 frags, 0.75 LDS-reads/MFMA). BK=64,
//       global_load_lds w=16 with SOURCE-side XOR swizzle (chunk ^= row&7) so
//       fragment ds_read_b128 is bank-conflict-free while keeping GLOAD's
//       lane-contiguous LDS dest. Epilogue: cross-wave LDS reduce, exactly-
//       once partial writes (direct s>=r, transposed s<r). No value atomics.
//   k2: 16-block fold over 32 slices -> done-counter last block -> out[0].

#define N_ROWS 4096
#define D_K    512
#define BT     128
#define BK     64
#define NTB    (N_ROWS / BT)           // 32
#define NTILES (NTB * (NTB + 1) / 2)   // 528
#define MARGIN 40.0f
#define FOLD_BLOCKS 16

typedef __bf16 bf16_t;
typedef bf16_t bf16x8 __attribute__((ext_vector_type(8)));
typedef float  floatx4 __attribute__((ext_vector_type(4)));
typedef unsigned short ushort_t;
typedef ushort_t ushortx8 __attribute__((ext_vector_type(8)));

#define GLOAD_LDS16(g, l)                                        \
    __builtin_amdgcn_global_load_lds(                            \
        (const __attribute__((address_space(1))) void*)(g),      \
        (__attribute__((address_space(3))) void*)(l), 16, 0, 0)

__device__ __forceinline__ ushort_t f2bf_rne(float x) {
    uint32_t u = __builtin_bit_cast(uint32_t, x);
    return (ushort_t)((u + 0x7FFFu + ((u >> 16) & 1u)) >> 16);
}

__global__ __launch_bounds__(256) void cast_kernel(
    const float* __restrict__ f, ushort_t* __restrict__ o,
    int* __restrict__ counter)
{
    const int gid = blockIdx.x * 256 + threadIdx.x;
    if (gid == 0) *counter = 0;

    const int i = gid * 8;
    const float4 v0 = *(const float4*)(f + i);
    const float4 v1 = *(const float4*)(f + i + 4);
    ushortx8 r;
    r[0] = f2bf_rne(v0.x); r[1] = f2bf_rne(v0.y);
    r[2] = f2bf_rne(v0.z); r[3] = f2bf_rne(v0.w);
    r[4] = f2bf_rne(v1.x); r[5] = f2bf_rne(v1.y);
    r[6] = f2bf_rne(v1.z); r[7] = f2bf_rne(v1.w);
    *(ushortx8*)(o + i) = r;
}

__global__ __launch_bounds__(512, 4) void gram_mfma_kernel(
    const ushort_t* __restrict__ fb, const int* __restrict__ tgt,
    float* __restrict__ ap_part, float* __restrict__ an_part)
{
    // [row][k] row-major, row stride 64 bf16 = 128 B; k-chunks (16 B) are
    // XOR-swizzled: physical chunk p holds global chunk p ^ (row & 7).
    __shared__ __align__(16) ushort_t As[BT * BK];   // 16 KB
    __shared__ __align__(16) ushort_t Bs[BT * BK];   // 16 KB
    __shared__ int tgI[BT];
    __shared__ int tgJ[BT];
    __shared__ float apRed[4][BT],  anRed[4][BT];    // direct, by wc
    __shared__ float apRedT[2][BT], anRedT[2][BT];   // transposed, by wr

    // flat block id -> upper-tri (bi, bj), row-major
    int bi = 0, rem = blockIdx.x;
    while (rem >= NTB - bi) { rem -= NTB - bi; ++bi; }
    const int bj = bi + rem;

    const int tid  = threadIdx.x;
    const int i0   = bi * BT;
    const int j0   = bj * BT;
    const int lane = tid & 63;
    const int wave = tid >> 6;
    const int wr   = wave >> 2;      // row half (0/1): 64 rows
    const int wc   = wave & 3;       // col quarter (0..3): 32 cols
    const int lr   = lane & 15;      // frag row (A/B) / col (C/D)
    const int lg   = lane >> 4;      // k-group (A/B) / row-quad (C/D)
    const int sw   = lr & 7;         // this lane's read-side swizzle key

    if (tid < BT)            tgI[tid]      = tgt[i0 + tid];
    else if (tid < 2 * BT)   tgJ[tid - BT] = tgt[j0 + tid - BT];

    // staging: thread t -> row t>>3 (and +64), physical chunk t&7 gets
    // global chunk (t&7)^(row&7). Dest = tid*16 (lane-contiguous per wave).
    const int srow = tid >> 3;
    const int schk = (tid & 7) ^ (srow & 7);
    const size_t gA0 = (size_t)(i0 + srow) * D_K + schk * 8;
    const size_t gB0 = (size_t)(j0 + srow) * D_K + schk * 8;
    const size_t gHi = (size_t)64 * D_K;
    char* AsB = (char*)As;
    char* BsB = (char*)Bs;

    floatx4 acc[4][2];
#pragma unroll
    for (int a = 0; a < 4; ++a)
#pragma unroll
        for (int b = 0; b < 2; ++b) acc[a][b] = (floatx4)0.0f;

    for (int k0 = 0; k0 < D_K; k0 += BK) {
        GLOAD_LDS16(fb + gA0 + k0,       AsB + tid * 16);
        GLOAD_LDS16(fb + gA0 + gHi + k0, AsB + 8192 + tid * 16);
        GLOAD_LDS16(fb + gB0 + k0,       BsB + tid * 16);
        GLOAD_LDS16(fb + gB0 + gHi + k0, BsB + 8192 + tid * 16);
        __syncthreads();

        bf16x8 af[2][4], bfr[2][2];
#pragma unroll
        for (int h = 0; h < 2; ++h) {
            const int pc = ((h * 4 + lg) ^ sw) * 8;   // swizzled k-chunk (elems)
#pragma unroll
            for (int rg = 0; rg < 4; ++rg)
                af[h][rg] = *(const bf16x8*)(As + (wr * 64 + rg * 16 + lr) * BK + pc);
#pragma unroll
            for (int cg = 0; cg < 2; ++cg)
                bfr[h][cg] = *(const bf16x8*)(Bs + (wc * 32 + cg * 16 + lr) * BK + pc);
        }
#pragma unroll
        for (int h = 0; h < 2; ++h)
#pragma unroll
            for (int rg = 0; rg < 4; ++rg)
#pragma unroll
                for (int cg = 0; cg < 2; ++cg)
                    acc[rg][cg] = __builtin_amdgcn_mfma_f32_16x16x32_bf16(
                        af[h][rg], bfr[h][cg], acc[rg][cg], 0, 0, 0);
        __syncthreads();
    }

    // ---- epilogue: C/D frag layout: col = lr, row = lg*4 + reg ----
    int tj[2];
#pragma unroll
    for (int cg = 0; cg < 2; ++cg) tj[cg] = tgJ[wc * 32 + cg * 16 + lr];

    float apT[2], anT[2];
#pragma unroll
    for (int cg = 0; cg < 2; ++cg) { apT[cg] = FLT_MAX; anT[cg] = -FLT_MAX; }

#pragma unroll
    for (int rg = 0; rg < 4; ++rg) {
#pragma unroll
        for (int r = 0; r < 4; ++r) {
            const int rloc = wr * 64 + rg * 16 + lg * 4 + r;
            const int ti = tgI[rloc];
            float vap = FLT_MAX, van = -FLT_MAX;
#pragma unroll
            for (int cg = 0; cg < 2; ++cg) {
                const float v = acc[rg][cg][r];
                if (ti == tj[cg]) { vap = fminf(vap, v); apT[cg] = fminf(apT[cg], v); }
                else              { van = fmaxf(van, v); anT[cg] = fmaxf(anT[cg], v); }
            }
            // direct: fold the 16 cols held by lanes lr=0..15
#pragma unroll
            for (int m = 1; m < 16; m <<= 1) {
                vap = fminf(vap, __shfl_xor(vap, m));
                van = fmaxf(van, __shfl_xor(van, m));
            }
            if (lr == 0) { apRed[wc][rloc] = vap; anRed[wc][rloc] = van; }
        }
    }
    // transposed: rows folded in-lane; fold the 4 lane-groups
#pragma unroll
    for (int cg = 0; cg < 2; ++cg) {
        float vap = apT[cg], van = anT[cg];
        vap = fminf(vap, __shfl_xor(vap, 16)); van = fmaxf(van, __shfl_xor(van, 16));
        vap = fminf(vap, __shfl_xor(vap, 32)); van = fmaxf(van, __shfl_xor(van, 32));
        if (lg == 0) {
            apRedT[wr][wc * 32 + cg * 16 + lr] = vap;
            anRedT[wr][wc * 32 + cg * 16 + lr] = van;
        }
    }
    __syncthreads();

    if (tid < BT) {
        const float ap = fminf(fminf(apRed[0][tid], apRed[1][tid]),
                               fminf(apRed[2][tid], apRed[3][tid]));
        const float an = fmaxf(fmaxf(anRed[0][tid], anRed[1][tid]),
                               fmaxf(anRed[2][tid], anRed[3][tid]));
        ap_part[(size_t)bj * N_ROWS + i0 + tid] = ap;
        an_part[(size_t)bj * N_ROWS + i0 + tid] = an;
        if (bi != bj) {
            ap_part[(size_t)bi * N_ROWS + j0 + tid] =
                fminf(apRedT[0][tid], apRedT[1][tid]);
            an_part[(size_t)bi * N_ROWS + j0 + tid] =
                fmaxf(anRedT[0][tid], anRedT[1][tid]);
        }
    }
}

__global__ __launch_bounds__(256) void fold_kernel(
    const float* __restrict__ ap_part, const float* __restrict__ an_part,
    float* __restrict__ blk_sum, int* __restrict__ counter,
    float* __restrict__ out)
{
    __shared__ float sred[4];
    const int tid = threadIdx.x;
    const int row = blockIdx.x * 256 + tid;
    const int lane = tid & 63;
    const int wave = tid >> 6;

    float ap = FLT_MAX, an = -FLT_MAX;
#pragma unroll 8
    for (int s = 0; s < NTB; ++s) {
        ap = fminf(ap, ap_part[(size_t)s * N_ROWS + row]);
        an = fmaxf(an, an_part[(size_t)s * N_ROWS + row]);
    }
    const float v = an - ap + MARGIN;
    float local = (v > 0.0f) ? v : 0.0f;
#pragma unroll
    for (int m = 32; m >= 1; m >>= 1) local += __shfl_down(local, m);
    if (lane == 0) sred[wave] = local;
    __syncthreads();

    if (tid == 0) {
        blk_sum[blockIdx.x] = sred[0] + sred[1] + sred[2] + sred[3];
        __threadfence();
        if (atomicAdd(counter, 1) == FOLD_BLOCKS - 1) {
            __threadfence();
            float s = 0.0f;
#pragma unroll
            for (int b = 0; b < FOLD_BLOCKS; ++b) s += blk_sum[b];
            out[0] = s * (1.0f / N_ROWS);
        }
    }
}

extern "C" void kernel_launch(void* const* d_in, const int* in_sizes, int n_in,
                              void* d_out, int out_size, void* d_ws, size_t ws_size,
                              hipStream_t stream)
{
    const float* feat = (const float*)d_in[0];
    const int*   tgt  = (const int*)d_in[1];

    ushort_t* fb      = (ushort_t*)d_ws;                        // 4 MB bf16 feat
    float*    ap_part = (float*)(fb + (size_t)N_ROWS * D_K);    // 512 KB
    float*    an_part = ap_part + (size_t)NTB * N_ROWS;         // 512 KB
    float*    blk_sum = an_part + (size_t)NTB * N_ROWS;         // 64 B
    int*      counter = (int*)(blk_sum + FOLD_BLOCKS);

    cast_kernel<<<(N_ROWS * D_K) / (256 * 8), 256, 0, stream>>>(feat, fb, counter);
    gram_mfma_kernel<<<NTILES, 512, 0, stream>>>(fb, tgt, ap_part, an_part);
    fold_kernel<<<FOLD_BLOCKS, 256, 0, stream>>>(ap_part, an_part, blk_sum,
                                                 counter, (float*)d_out);
}

// Round 9
// 86.551 us; speedup vs baseline: 2.6338x; 1.0023x over previous
//
#include <hip/hip_runtime.h>
#include <float.h>
#include <stdint.h>

// CorrLoss via bf16 MFMA, symmetric 128x128 tiles, swizzled LDS, no atomics.
//   Round 9: occupancy push. Epilogue-reduction LDS aliased into As (33.5 KB
//   total), fragment regs halved via sequential h-halves, launch_bounds(512,6)
//   -> target 3 blocks/CU (24 waves) vs R8's 2 (16 waves).
//   k0: cast fp32->bf16 (RNE); zero fold counter.
//   k1: 528 upper-tri tiles, 8 waves x (64x32 patch), BK=64, XOR-swizzled
//       global_load_lds w=16 staging; exactly-once partial writes.
//   k2: 16-block fold -> done-counter last block -> out[0].

#define N_ROWS 4096
#define D_K    512
#define BT     128
#define BK     64
#define NTB    (N_ROWS / BT)           // 32
#define NTILES (NTB * (NTB + 1) / 2)   // 528
#define MARGIN 40.0f
#define FOLD_BLOCKS 16

typedef __bf16 bf16_t;
typedef bf16_t bf16x8 __attribute__((ext_vector_type(8)));
typedef float  floatx4 __attribute__((ext_vector_type(4)));
typedef unsigned short ushort_t;
typedef ushort_t ushortx8 __attribute__((ext_vector_type(8)));

#define GLOAD_LDS16(g, l)                                        \
    __builtin_amdgcn_global_load_lds(                            \
        (const __attribute__((address_space(1))) void*)(g),      \
        (__attribute__((address_space(3))) void*)(l), 16, 0, 0)

__device__ __forceinline__ ushort_t f2bf_rne(float x) {
    uint32_t u = __builtin_bit_cast(uint32_t, x);
    return (ushort_t)((u + 0x7FFFu + ((u >> 16) & 1u)) >> 16);
}

__global__ __launch_bounds__(256) void cast_kernel(
    const float* __restrict__ f, ushort_t* __restrict__ o,
    int* __restrict__ counter)
{
    const int gid = blockIdx.x * 256 + threadIdx.x;
    if (gid == 0) *counter = 0;

    const int i = gid * 8;
    const float4 v0 = *(const float4*)(f + i);
    const float4 v1 = *(const float4*)(f + i + 4);
    ushortx8 r;
    r[0] = f2bf_rne(v0.x); r[1] = f2bf_rne(v0.y);
    r[2] = f2bf_rne(v0.z); r[3] = f2bf_rne(v0.w);
    r[4] = f2bf_rne(v1.x); r[5] = f2bf_rne(v1.y);
    r[6] = f2bf_rne(v1.z); r[7] = f2bf_rne(v1.w);
    *(ushortx8*)(o + i) = r;
}

__global__ __launch_bounds__(512, 6) void gram_mfma_kernel(
    const ushort_t* __restrict__ fb, const int* __restrict__ tgt,
    float* __restrict__ ap_part, float* __restrict__ an_part)
{
    // [row][k] row-major, row stride 64 bf16 = 128 B; 16 B k-chunks
    // XOR-swizzled: physical chunk p holds global chunk p ^ (row & 7).
    __shared__ __align__(16) ushort_t As[BT * BK];   // 16 KB
    __shared__ __align__(16) ushort_t Bs[BT * BK];   // 16 KB
    __shared__ int tgI[BT];
    __shared__ int tgJ[BT];

    // epilogue reductions alias As (used only after the K-loop's last barrier)
    float* apRed  = (float*)As;          // [4][BT]
    float* anRed  = apRed  + 4 * BT;     // [4][BT]
    float* apRedT = anRed  + 4 * BT;     // [2][BT]
    float* anRedT = apRedT + 2 * BT;     // [2][BT]   total 6 KB <= 16 KB

    // flat block id -> upper-tri (bi, bj), row-major
    int bi = 0, rem = blockIdx.x;
    while (rem >= NTB - bi) { rem -= NTB - bi; ++bi; }
    const int bj = bi + rem;

    const int tid  = threadIdx.x;
    const int i0   = bi * BT;
    const int j0   = bj * BT;
    const int lane = tid & 63;
    const int wave = tid >> 6;
    const int wr   = wave >> 2;      // row half (0/1): 64 rows
    const int wc   = wave & 3;       // col quarter (0..3): 32 cols
    const int lr   = lane & 15;      // frag row (A/B) / col (C/D)
    const int lg   = lane >> 4;      // k-group (A/B) / row-quad (C/D)
    const int sw   = lr & 7;         // read-side swizzle key

    if (tid < BT)            tgI[tid]      = tgt[i0 + tid];
    else if (tid < 2 * BT)   tgJ[tid - BT] = tgt[j0 + tid - BT];

    // staging: thread t -> row t>>3 (and +64), physical chunk t&7 holds
    // global chunk (t&7)^(row&7); dest = tid*16 (lane-contiguous per wave)
    const int srow = tid >> 3;
    const int schk = (tid & 7) ^ (srow & 7);
    const size_t gA0 = (size_t)(i0 + srow) * D_K + schk * 8;
    const size_t gB0 = (size_t)(j0 + srow) * D_K + schk * 8;
    const size_t gHi = (size_t)64 * D_K;
    char* AsB = (char*)As;
    char* BsB = (char*)Bs;

    floatx4 acc[4][2];
#pragma unroll
    for (int a = 0; a < 4; ++a)
#pragma unroll
        for (int b = 0; b < 2; ++b) acc[a][b] = (floatx4)0.0f;

    for (int k0 = 0; k0 < D_K; k0 += BK) {
        GLOAD_LDS16(fb + gA0 + k0,       AsB + tid * 16);
        GLOAD_LDS16(fb + gA0 + gHi + k0, AsB + 8192 + tid * 16);
        GLOAD_LDS16(fb + gB0 + k0,       BsB + tid * 16);
        GLOAD_LDS16(fb + gB0 + gHi + k0, BsB + 8192 + tid * 16);
        __syncthreads();

        // two sequential k-halves; frag regs scoped per-half (VGPR diet)
#pragma unroll
        for (int h = 0; h < 2; ++h) {
            bf16x8 af[4], bfr[2];
            const int pc = ((h * 4 + lg) ^ sw) * 8;   // swizzled chunk (elems)
#pragma unroll
            for (int rg = 0; rg < 4; ++rg)
                af[rg] = *(const bf16x8*)(As + (wr * 64 + rg * 16 + lr) * BK + pc);
#pragma unroll
            for (int cg = 0; cg < 2; ++cg)
                bfr[cg] = *(const bf16x8*)(Bs + (wc * 32 + cg * 16 + lr) * BK + pc);
#pragma unroll
            for (int rg = 0; rg < 4; ++rg)
#pragma unroll
                for (int cg = 0; cg < 2; ++cg)
                    acc[rg][cg] = __builtin_amdgcn_mfma_f32_16x16x32_bf16(
                        af[rg], bfr[cg], acc[rg][cg], 0, 0, 0);
        }
        __syncthreads();
    }

    // ---- epilogue: C/D frag layout: col = lr, row = lg*4 + reg ----
    int tj[2];
#pragma unroll
    for (int cg = 0; cg < 2; ++cg) tj[cg] = tgJ[wc * 32 + cg * 16 + lr];

    float apT[2], anT[2];
#pragma unroll
    for (int cg = 0; cg < 2; ++cg) { apT[cg] = FLT_MAX; anT[cg] = -FLT_MAX; }

#pragma unroll
    for (int rg = 0; rg < 4; ++rg) {
#pragma unroll
        for (int r = 0; r < 4; ++r) {
            const int rloc = wr * 64 + rg * 16 + lg * 4 + r;
            const int ti = tgI[rloc];
            float vap = FLT_MAX, van = -FLT_MAX;
#pragma unroll
            for (int cg = 0; cg < 2; ++cg) {
                const float v = acc[rg][cg][r];
                if (ti == tj[cg]) { vap = fminf(vap, v); apT[cg] = fminf(apT[cg], v); }
                else              { van = fmaxf(van, v); anT[cg] = fmaxf(anT[cg], v); }
            }
            // direct: fold the 16 cols held by lanes lr=0..15
#pragma unroll
            for (int m = 1; m < 16; m <<= 1) {
                vap = fminf(vap, __shfl_xor(vap, m));
                van = fmaxf(van, __shfl_xor(van, m));
            }
            if (lr == 0) { apRed[wc * BT + rloc] = vap; anRed[wc * BT + rloc] = van; }
        }
    }
    // transposed: rows folded in-lane; fold the 4 lane-groups
#pragma unroll
    for (int cg = 0; cg < 2; ++cg) {
        float vap = apT[cg], van = anT[cg];
        vap = fminf(vap, __shfl_xor(vap, 16)); van = fmaxf(van, __shfl_xor(van, 16));
        vap = fminf(vap, __shfl_xor(vap, 32)); van = fmaxf(van, __shfl_xor(van, 32));
        if (lg == 0) {
            apRedT[wr * BT + wc * 32 + cg * 16 + lr] = vap;
            anRedT[wr * BT + wc * 32 + cg * 16 + lr] = van;
        }
    }
    __syncthreads();

    if (tid < BT) {
        const float ap = fminf(fminf(apRed[0 * BT + tid], apRed[1 * BT + tid]),
                               fminf(apRed[2 * BT + tid], apRed[3 * BT + tid]));
        const float an = fmaxf(fmaxf(anRed[0 * BT + tid], anRed[1 * BT + tid]),
                               fmaxf(anRed[2 * BT + tid], anRed[3 * BT + tid]));
        ap_part[(size_t)bj * N_ROWS + i0 + tid] = ap;
        an_part[(size_t)bj * N_ROWS + i0 + tid] = an;
        if (bi != bj) {
            ap_part[(size_t)bi * N_ROWS + j0 + tid] =
                fminf(apRedT[0 * BT + tid], apRedT[1 * BT + tid]);
            an_part[(size_t)bi * N_ROWS + j0 + tid] =
                fmaxf(anRedT[0 * BT + tid], anRedT[1 * BT + tid]);
        }
    }
}

__global__ __launch_bounds__(256) void fold_kernel(
    const float* __restrict__ ap_part, const float* __restrict__ an_part,
    float* __restrict__ blk_sum, int* __restrict__ counter,
    float* __restrict__ out)
{
    __shared__ float sred[4];
    const int tid = threadIdx.x;
    const int row = blockIdx.x * 256 + tid;
    const int lane = tid & 63;
    const int wave = tid >> 6;

    float ap = FLT_MAX, an = -FLT_MAX;
#pragma unroll 8
    for (int s = 0; s < NTB; ++s) {
        ap = fminf(ap, ap_part[(size_t)s * N_ROWS + row]);
        an = fmaxf(an, an_part[(size_t)s * N_ROWS + row]);
    }
    const float v = an - ap + MARGIN;
    float local = (v > 0.0f) ? v : 0.0f;
#pragma unroll
    for (int m = 32; m >= 1; m >>= 1) local += __shfl_down(local, m);
    if (lane == 0) sred[wave] = local;
    __syncthreads();

    if (tid == 0) {
        blk_sum[blockIdx.x] = sred[0] + sred[1] + sred[2] + sred[3];
        __threadfence();
        if (atomicAdd(counter, 1) == FOLD_BLOCKS - 1) {
            __threadfence();
            float s = 0.0f;
#pragma unroll
            for (int b = 0; b < FOLD_BLOCKS; ++b) s += blk_sum[b];
            out[0] = s * (1.0f / N_ROWS);
        }
    }
}

extern "C" void kernel_launch(void* const* d_in, const int* in_sizes, int n_in,
                              void* d_out, int out_size, void* d_ws, size_t ws_size,
                              hipStream_t stream)
{
    const float* feat = (const float*)d_in[0];
    const int*   tgt  = (const int*)d_in[1];

    ushort_t* fb      = (ushort_t*)d_ws;                        // 4 MB bf16 feat
    float*    ap_part = (float*)(fb + (size_t)N_ROWS * D_K);    // 512 KB
    float*    an_part = ap_part + (size_t)NTB * N_ROWS;         // 512 KB
    float*    blk_sum = an_part + (size_t)NTB * N_ROWS;         // 64 B
    int*      counter = (int*)(blk_sum + FOLD_BLOCKS);

    cast_kernel<<<(N_ROWS * D_K) / (256 * 8), 256, 0, stream>>>(feat, fb, counter);
    gram_mfma_kernel<<<NTILES, 512, 0, stream>>>(fb, tgt, ap_part, an_part);
    fold_kernel<<<FOLD_BLOCKS, 256, 0, stream>>>(ap_part, an_part, blk_sum,
                                                 counter, (float*)d_out);
}